// Round 1
// baseline (210.177 us; speedup 1.0000x reference)
//
#include <hip/hip_runtime.h>
#include <hip/hip_bf16.h>
#include <cstdint>
#include <cstddef>

// Problem: B=8, S=512, D=768, HEADS=16, HD=64
//   qk = hidden(4096x768) @ W(768x2048) + b      -> bf16 MFMA GEMM
//   q,k split + interleaved RoPE                 -> relayout to (B,H,S,64)
//   logits[b,h,m,n] = <q,k>/8 - masks            -> 128 batched 512x512x64 MFMA
//   tri_mask[b,m,n]                              -> elementwise
// Tolerance is ~2e10 absmax (NEG=1e12 dominates ref absmax) -> bf16 is safe.

#define NEGV 1.0e12f

typedef short bf16x8 __attribute__((ext_vector_type(8)));
typedef float f32x4  __attribute__((ext_vector_type(4)));

static __device__ __forceinline__ short f2b(float x) {
    __hip_bfloat16 h = __float2bfloat16(x);
    union { __hip_bfloat16 h; short s; } u; u.h = h; return u.s;
}
static __device__ __forceinline__ float b2f(short s) {
    union { short s; __hip_bfloat16 h; } u; u.s = s; return __bfloat162float(u.h);
}

// ---------------------------------------------------------------------------
// 1) cast hidden -> Xb (bf16, 4096x768) ; transpose+cast W -> Wt (bf16, 2048x768)
//    (Wt is W^T so the GEMM B-operand is K-contiguous for ds_read_b128 frags)
// ---------------------------------------------------------------------------
__global__ __launch_bounds__(256) void cast_kernel(const float* __restrict__ hidden,
                                                   const float* __restrict__ W,
                                                   short* __restrict__ Xb,
                                                   short* __restrict__ Wt) {
    const int E1 = 4096 * 768;      // hidden elements
    const int E2 = 768 * 2048;      // W elements
    int i = blockIdx.x * 256 + threadIdx.x;
    if (i < E1) {
        Xb[i] = f2b(hidden[i]);
    } else if (i < E1 + E2) {
        int j = i - E1;             // j = n*768 + k  (coalesced write)
        int n = j / 768, k = j - n * 768;
        Wt[j] = f2b(W[k * 2048 + n]);   // strided read (small, L2-cached)
    }
}

// ---------------------------------------------------------------------------
// 2) GEMM1: C(4096x2048,bf16) = A(4096x768,bf16) @ Wt^T + bias
//    128x128 tile, 4 waves, 16x16x32 bf16 MFMA, BK=32, single-buffered LDS.
//    A-frag: A[m=lane&15][k=quad*8+j]; B-frag: B[k=quad*8+j][n=lane&15]
//    C/D:    col=lane&15, row=quad*4+reg   (verified layouts, learn_hip m89/m91)
// ---------------------------------------------------------------------------
__global__ __launch_bounds__(256) void gemm_qk(const short* __restrict__ A,
                                               const short* __restrict__ Bt,
                                               const float* __restrict__ bias,
                                               short* __restrict__ C) {
    __shared__ short As[128 * 32];
    __shared__ short Bs[128 * 32];
    const int m0 = (blockIdx.x >> 4) * 128;   // 32 m-tiles
    const int n0 = (blockIdx.x & 15) * 128;   // 16 n-tiles
    const int tid  = threadIdx.x;
    const int wave = tid >> 6, lane = tid & 63;
    const int quad = lane >> 4, r16 = lane & 15;
    const int wm = (wave >> 1) * 64, wn = (wave & 1) * 64;

    // staging map: thread covers rows (srow, 64+srow), 8 shorts at scol
    const int srow = tid >> 2;          // 0..63
    const int scol = (tid & 3) * 8;     // 0,8,16,24
    const short* Ap0 = A  + (m0 + srow) * 768 + scol;
    const short* Ap1 = A  + (m0 + 64 + srow) * 768 + scol;
    const short* Bp0 = Bt + (n0 + srow) * 768 + scol;
    const short* Bp1 = Bt + (n0 + 64 + srow) * 768 + scol;
    short* As0 = As + srow * 32 + scol;
    short* As1 = As + (64 + srow) * 32 + scol;
    short* Bs0 = Bs + srow * 32 + scol;
    short* Bs1 = Bs + (64 + srow) * 32 + scol;

    f32x4 acc[4][4] = {};

    for (int k0 = 0; k0 < 768; k0 += 32) {
        __syncthreads();   // previous iter's frag reads done before overwrite
        *(bf16x8*)As0 = *(const bf16x8*)(Ap0 + k0);
        *(bf16x8*)As1 = *(const bf16x8*)(Ap1 + k0);
        *(bf16x8*)Bs0 = *(const bf16x8*)(Bp0 + k0);
        *(bf16x8*)Bs1 = *(const bf16x8*)(Bp1 + k0);
        __syncthreads();

        bf16x8 af[4], bfr[4];
#pragma unroll
        for (int mi = 0; mi < 4; ++mi)
            af[mi] = *(const bf16x8*)(As + (wm + mi * 16 + r16) * 32 + quad * 8);
#pragma unroll
        for (int ni = 0; ni < 4; ++ni)
            bfr[ni] = *(const bf16x8*)(Bs + (wn + ni * 16 + r16) * 32 + quad * 8);
#pragma unroll
        for (int mi = 0; mi < 4; ++mi)
#pragma unroll
            for (int ni = 0; ni < 4; ++ni)
                acc[mi][ni] = __builtin_amdgcn_mfma_f32_16x16x32_bf16(
                    af[mi], bfr[ni], acc[mi][ni], 0, 0, 0);
    }

#pragma unroll
    for (int mi = 0; mi < 4; ++mi)
#pragma unroll
        for (int ni = 0; ni < 4; ++ni) {
            int col = n0 + wn + ni * 16 + r16;
            float bv = bias[col];
            int rowb = m0 + wm + mi * 16 + quad * 4;
#pragma unroll
            for (int r = 0; r < 4; ++r)
                C[(rowb + r) * 2048 + col] = f2b(acc[mi][ni][r] + bv);
        }
}

// ---------------------------------------------------------------------------
// 3) RoPE + relayout: QKi(B,S,H,2,64) -> Q,K (B,H,S,64) bf16
//    out[2i]   = x[2i]*cos(f_i) - x[2i+1]*sin(f_i)
//    out[2i+1] = x[2i+1]*cos(f_i) + x[2i]*sin(f_i),  f_i = s * 10000^(-2i/64)
// ---------------------------------------------------------------------------
__global__ __launch_bounds__(256) void rope_kernel(const short* __restrict__ QK,
                                                   short* __restrict__ Q,
                                                   short* __restrict__ K) {
    int t = blockIdx.x * 256 + threadIdx.x;     // 4,194,304 threads
    int i = t & 31;
    int rr = t >> 5;
    int which = rr & 1; rr >>= 1;
    int h = rr & 15;    rr >>= 4;
    int s = rr & 511;
    int b = rr >> 9;

    int src = (b * 512 + s) * 2048 + h * 128 + which * 64 + 2 * i;
    float f0 = b2f(QK[src]), f1 = b2f(QK[src + 1]);

    // inv_freq = 2^(-i * log2(10000)*2/64)
    float ang = (float)s * exp2f(-0.4152410118609203f * (float)i);
    float sn, cs;
    __sincosf(ang, &sn, &cs);
    float o0 = f0 * cs - f1 * sn;
    float o1 = f1 * cs + f0 * sn;

    short* dst = (which ? K : Q) + ((b * 16 + h) * 512 + s) * 64 + 2 * i;
    dst[0] = f2b(o0);
    dst[1] = f2b(o1);
}

// ---------------------------------------------------------------------------
// 4) logits: per (b,h, 128x128 tile):  acc = Q_tile @ K_tile^T, K-dim = 64
//    epilogue: *0.125 - rowNeg - colNeg - (m>n)*NEG, fp32 store
// ---------------------------------------------------------------------------
__global__ __launch_bounds__(256) void logits_kernel(const short* __restrict__ Q,
                                                     const short* __restrict__ K,
                                                     const int* __restrict__ tok,
                                                     float* __restrict__ out) {
    __shared__ short Qs[128 * 64];
    __shared__ short Ks[128 * 64];
    __shared__ float rowNeg[128];
    __shared__ float colNeg[128];

    int blk = blockIdx.x;                 // 2048 = 128 (b*h) * 4 * 4
    int nt = blk & 3, mt = (blk >> 2) & 3, bh = blk >> 4;
    int b = bh >> 4;
    int m0 = mt * 128, n0 = nt * 128;

    const int tid  = threadIdx.x;
    const int wave = tid >> 6, lane = tid & 63;
    const int quad = lane >> 4, r16 = lane & 15;
    const int wm = (wave >> 1) * 64, wn = (wave & 1) * 64;

    const short* Qbase = Q + (bh * 512 + m0) * 64;   // contiguous 8192 shorts
    const short* Kbase = K + (bh * 512 + n0) * 64;
#pragma unroll
    for (int p = 0; p < 4; ++p) {
        int e = p * 2048 + tid * 8;
        *(bf16x8*)(Qs + e) = *(const bf16x8*)(Qbase + e);
        *(bf16x8*)(Ks + e) = *(const bf16x8*)(Kbase + e);
    }
    if (tid < 128)        rowNeg[tid]        = (tok[b * 512 + m0 + tid] > 0) ? 0.f : NEGV;
    else if (tid < 256)   colNeg[tid - 128]  = (tok[b * 512 + n0 + (tid - 128)] > 0) ? 0.f : NEGV;
    __syncthreads();

    f32x4 acc[4][4] = {};
#pragma unroll
    for (int kk = 0; kk < 64; kk += 32) {
        bf16x8 af[4], bfr[4];
#pragma unroll
        for (int mi = 0; mi < 4; ++mi)
            af[mi] = *(const bf16x8*)(Qs + (wm + mi * 16 + r16) * 64 + kk + quad * 8);
#pragma unroll
        for (int ni = 0; ni < 4; ++ni)
            bfr[ni] = *(const bf16x8*)(Ks + (wn + ni * 16 + r16) * 64 + kk + quad * 8);
#pragma unroll
        for (int mi = 0; mi < 4; ++mi)
#pragma unroll
            for (int ni = 0; ni < 4; ++ni)
                acc[mi][ni] = __builtin_amdgcn_mfma_f32_16x16x32_bf16(
                    af[mi], bfr[ni], acc[mi][ni], 0, 0, 0);
    }

    float* obase = out + (size_t)bh * 512 * 512;
#pragma unroll
    for (int mi = 0; mi < 4; ++mi)
#pragma unroll
        for (int ni = 0; ni < 4; ++ni) {
            int n = n0 + wn + ni * 16 + r16;
            float cn = colNeg[n - n0];
#pragma unroll
            for (int r = 0; r < 4; ++r) {
                int m = m0 + wm + mi * 16 + quad * 4 + r;
                float v = acc[mi][ni][r] * 0.125f - rowNeg[m - m0] - cn
                          - ((m > n) ? NEGV : 0.0f);
                obase[(size_t)m * 512 + n] = v;
            }
        }
}

// ---------------------------------------------------------------------------
// 5) tri_mask[b,m,n] = (m>n ? 0 : 1) * mask[b,m] * mask[b,n]
// ---------------------------------------------------------------------------
__global__ __launch_bounds__(256) void trimask_kernel(const int* __restrict__ tok,
                                                      float* __restrict__ out2) {
    int t = blockIdx.x * 256 + threadIdx.x;   // 524,288 threads (4 floats each)
    int n4 = (t & 127) << 2;
    int rr = t >> 7;
    int m = rr & 511;
    int b = rr >> 9;
    float mm = (tok[b * 512 + m] > 0) ? 1.0f : 0.0f;
    f32x4 v;
#pragma unroll
    for (int j = 0; j < 4; ++j) {
        int n = n4 + j;
        float mn = (tok[b * 512 + n] > 0) ? 1.0f : 0.0f;
        v[j] = (m > n) ? 0.0f : (mm * mn);
    }
    *(f32x4*)(out2 + (size_t)(b * 512 + m) * 512 + n4) = v;
}

// ---------------------------------------------------------------------------
extern "C" void kernel_launch(void* const* d_in, const int* in_sizes, int n_in,
                              void* d_out, int out_size, void* d_ws, size_t ws_size,
                              hipStream_t stream) {
    const float* hidden = (const float*)d_in[0];   // (8,512,768) fp32
    const int*   tok    = (const int*)d_in[1];     // (8,512) int32
    const float* W      = (const float*)d_in[2];   // (768,2048) fp32
    const float* bias   = (const float*)d_in[3];   // (2048,) fp32
    float* out  = (float*)d_out;                   // logits: 33,554,432 floats
    float* out2 = out + 33554432;                  // tri_mask: 2,097,152 floats

    // workspace layout (32 MiB total, lifetimes disjoint where aliased):
    //   [0,16M)        QKi  bf16 4096x2048   (gemm out, dead after rope)
    //   [16M,22.3M)    Xb   bf16 4096x768    (dead after gemm)   } aliased with
    //   [22M,25.1M)    Wt   bf16 2048x768    (dead after gemm)   } Q below
    //   [16M,24M)      Q    bf16 (B,H,S,64)  (written by rope)
    //   [24M,32M)      K    bf16 (B,H,S,64)
    char* ws = (char*)d_ws;
    short* QKi = (short*)(ws);
    short* Xb  = (short*)(ws + 16777216);
    short* Wt  = (short*)(ws + 23068672);
    short* Qb  = (short*)(ws + 16777216);   // aliases Xb/Wt (disjoint lifetime)
    short* Kb  = (short*)(ws + 25165824);

    hipLaunchKernelGGL(cast_kernel,    dim3(18432), dim3(256), 0, stream, hidden, W, Xb, Wt);
    hipLaunchKernelGGL(gemm_qk,        dim3(512),   dim3(256), 0, stream, Xb, Wt, bias, QKi);
    hipLaunchKernelGGL(rope_kernel,    dim3(16384), dim3(256), 0, stream, QKi, Qb, Kb);
    hipLaunchKernelGGL(logits_kernel,  dim3(2048),  dim3(256), 0, stream, Qb, Kb, tok, out);
    hipLaunchKernelGGL(trimask_kernel, dim3(2048),  dim3(256), 0, stream, tok, out2);
}

// Round 2
// 198.805 us; speedup vs baseline: 1.0572x; 1.0572x over previous
//
#include <hip/hip_runtime.h>
#include <hip/hip_bf16.h>
#include <cstdint>
#include <cstddef>

// Problem: B=8, S=512, D=768, HEADS=16, HD=64
//   qk = hidden(4096x768) @ W(768x2048) + b      -> bf16 MFMA GEMM (global_load_lds)
//   RoPE fused into logits staging (sin/cos from precomputed table)
//   logits[b,h,m,n] = <q,k>/8 - masks            -> 128 batched 512x512x64 MFMA
//   tri_mask fused into h==0 logits blocks
// Tolerance ~2e10 absmax (NEG=1e12 dominates) -> bf16 numerically free (R0: 1.2e-2).

#define NEGV 1.0e12f

typedef short bf16x8 __attribute__((ext_vector_type(8)));
typedef float f32x4  __attribute__((ext_vector_type(4)));

static __device__ __forceinline__ short f2b(float x) {
    __hip_bfloat16 h = __float2bfloat16(x);
    union { __hip_bfloat16 h; short s; } u; u.h = h; return u.s;
}
static __device__ __forceinline__ float b2f(short s) {
    union { short s; __hip_bfloat16 h; } u; u.s = s; return __bfloat162float(u.h);
}

// async global->LDS, 16B/lane; LDS dest = wave-uniform base + lane*16
static __device__ __forceinline__ void gload16(const short* g, short* l) {
    __builtin_amdgcn_global_load_lds(
        (const __attribute__((address_space(1))) void*)g,
        (__attribute__((address_space(3))) void*)l, 16, 0, 0);
}

// ---------------------------------------------------------------------------
// 1) prep: cast hidden -> Xb bf16 (vectorized), and build sin/cos RoPE table
//    SinT/CosT[s*32+i] = sincos(s * 10000^(-i/32)), s<512, i<32
// ---------------------------------------------------------------------------
__global__ __launch_bounds__(256) void prep_kernel(const float* __restrict__ hidden,
                                                   short* __restrict__ Xb,
                                                   float* __restrict__ SinT,
                                                   float* __restrict__ CosT) {
    int t = blockIdx.x * 256 + threadIdx.x;
    if (t < 393216) {                       // 3,145,728 floats / 8
        const float4* hp = (const float4*)hidden;
        float4 a = hp[t * 2];
        float4 c = hp[t * 2 + 1];
        bf16x8 v;
        v[0] = f2b(a.x); v[1] = f2b(a.y); v[2] = f2b(a.z); v[3] = f2b(a.w);
        v[4] = f2b(c.x); v[5] = f2b(c.y); v[6] = f2b(c.z); v[7] = f2b(c.w);
        *(bf16x8*)(Xb + t * 8) = v;
    } else if (t < 393216 + 16384) {
        int u = t - 393216;
        int s = u >> 5, i = u & 31;
        float ang = (float)s * exp2f(-0.4152410118609203f * (float)i); // log2(1e4)/32
        float sn, cs;
        __sincosf(ang, &sn, &cs);
        SinT[u] = sn;
        CosT[u] = cs;
    }
}

// ---------------------------------------------------------------------------
// 2) LDS-tiled transpose+cast: W(768x2048 fp32, KxN) -> Wt(2048x768 bf16, NxK)
//    64x64 tiles; coalesced reads (along n) AND coalesced writes (along k).
// ---------------------------------------------------------------------------
__global__ __launch_bounds__(256) void transpose_w(const float* __restrict__ W,
                                                   short* __restrict__ Wt) {
    __shared__ short T[64 * 68];            // pad 68 to break bank stride
    int k0 = (blockIdx.x % 12) * 64;
    int n0 = (blockIdx.x / 12) * 64;
    int tid = threadIdx.x;

    // load: row r=k, 4 float4 per thread, contiguous 64B per 4 lanes
    int r = tid >> 2;
    int cbase = (tid & 3) * 4;
#pragma unroll
    for (int q = 0; q < 4; ++q) {
        int c = cbase + q * 16;
        float4 v = *(const float4*)(W + (size_t)(k0 + r) * 2048 + n0 + c);
        short* tp = T + r * 68 + c;
        tp[0] = f2b(v.x); tp[1] = f2b(v.y); tp[2] = f2b(v.z); tp[3] = f2b(v.w);
    }
    __syncthreads();

    // store: out-row n = tid>>2, 16 k-elements, contiguous 128B per 4 lanes
    int n = tid >> 2;
    int kc = (tid & 3) * 16;
    bf16x8 o0, o1;
#pragma unroll
    for (int j = 0; j < 8; ++j) {
        o0[j] = T[(kc + j) * 68 + n];
        o1[j] = T[(kc + 8 + j) * 68 + n];
    }
    short* wp = Wt + (size_t)(n0 + n) * 768 + k0 + kc;
    *(bf16x8*)wp       = o0;
    *(bf16x8*)(wp + 8) = o1;
}

// ---------------------------------------------------------------------------
// 3) GEMM1: C(4096x2048,bf16) = A(4096x768) @ Wt^T + bias
//    128x128 tile, 4 waves, 16x16x32 bf16 MFMA, BK=32,
//    global_load_lds width=16 staging (m97 structure, ~874 TF class).
// ---------------------------------------------------------------------------
__global__ __launch_bounds__(256) void gemm_qk(const short* __restrict__ A,
                                               const short* __restrict__ Bt,
                                               const float* __restrict__ bias,
                                               short* __restrict__ C) {
    __shared__ short As[128 * 32];
    __shared__ short Bs[128 * 32];
    const int m0 = (blockIdx.x >> 4) * 128;   // 32 m-tiles
    const int n0 = (blockIdx.x & 15) * 128;   // 16 n-tiles
    const int tid  = threadIdx.x;
    const int wave = tid >> 6, lane = tid & 63;
    const int quad = lane >> 4, r16 = lane & 15;
    const int wm = (wave >> 1) * 64, wn = (wave & 1) * 64;

    // staging: wave w covers rows [w*32, w*32+32); lane i -> row i>>2, col (i&3)*8
    const int srow = wave * 32 + (lane >> 2);
    const int scol = (lane & 3) * 8;
    const short* gA0 = A  + (size_t)(m0 + srow) * 768 + scol;
    const short* gA1 = gA0 + 16 * 768;
    const short* gB0 = Bt + (size_t)(n0 + srow) * 768 + scol;
    const short* gB1 = gB0 + 16 * 768;
    short* lA0 = As + (wave * 32) * 32;       // wave-uniform LDS bases
    short* lA1 = As + (wave * 32 + 16) * 32;
    short* lB0 = Bs + (wave * 32) * 32;
    short* lB1 = Bs + (wave * 32 + 16) * 32;

    f32x4 acc[4][4] = {};

    for (int k0 = 0; k0 < 768; k0 += 32) {
        __syncthreads();                       // drain prev iter's ds_reads
        gload16(gA0 + k0, lA0);
        gload16(gA1 + k0, lA1);
        gload16(gB0 + k0, lB0);
        gload16(gB1 + k0, lB1);
        __syncthreads();                       // drains vmcnt(0) -> LDS valid

        bf16x8 af[4], bfr[4];
#pragma unroll
        for (int mi = 0; mi < 4; ++mi)
            af[mi] = *(const bf16x8*)(As + (wm + mi * 16 + r16) * 32 + quad * 8);
#pragma unroll
        for (int ni = 0; ni < 4; ++ni)
            bfr[ni] = *(const bf16x8*)(Bs + (wn + ni * 16 + r16) * 32 + quad * 8);
#pragma unroll
        for (int mi = 0; mi < 4; ++mi)
#pragma unroll
            for (int ni = 0; ni < 4; ++ni)
                acc[mi][ni] = __builtin_amdgcn_mfma_f32_16x16x32_bf16(
                    af[mi], bfr[ni], acc[mi][ni], 0, 0, 0);
    }

#pragma unroll
    for (int mi = 0; mi < 4; ++mi)
#pragma unroll
        for (int ni = 0; ni < 4; ++ni) {
            int col = n0 + wn + ni * 16 + r16;
            float bv = bias[col];
            int rowb = m0 + wm + mi * 16 + quad * 4;
#pragma unroll
            for (int r = 0; r < 4; ++r)
                C[(size_t)(rowb + r) * 2048 + col] = f2b(acc[mi][ni][r] + bv);
        }
}

// ---------------------------------------------------------------------------
// 4) logits: per (b,h, 128x128 tile). Stages Q/K tiles directly from QKi
//    (B,S,H,2,64) with RoPE applied in-register (table lookup), LDS row
//    stride 72 shorts (144B) -> 2-way banks (free). Fuses tri_mask (h==0).
// ---------------------------------------------------------------------------
__global__ __launch_bounds__(256) void logits_kernel(const short* __restrict__ QKi,
                                                     const float* __restrict__ SinT,
                                                     const float* __restrict__ CosT,
                                                     const int* __restrict__ tok,
                                                     float* __restrict__ out,
                                                     float* __restrict__ out2) {
    __shared__ short Qs[128 * 72];
    __shared__ short Ks[128 * 72];
    __shared__ float rowNeg[128];
    __shared__ float colNeg[128];

    int blk = blockIdx.x;                 // 2048 = 128 (b*h) * 4 * 4
    int nt = blk & 3, mt = (blk >> 2) & 3, bh = blk >> 4;
    int b = bh >> 4, h = bh & 15;
    int m0 = mt * 128, n0 = nt * 128;

    const int tid  = threadIdx.x;
    const int wave = tid >> 6, lane = tid & 63;
    const int quad = lane >> 4, r16 = lane & 15;
    const int wm = (wave >> 1) * 64, wn = (wave & 1) * 64;

    // ---- staged load + RoPE: thread covers one Q-row-half and one K-row-half
    int row = tid >> 1;
    int ch  = (tid & 1) * 32;                 // 32-short half-row
    int sQ = m0 + row, sK = n0 + row;
    const short* qsrc = QKi + ((size_t)(b * 512 + sQ)) * 2048 + h * 128 + ch;
    const short* ksrc = QKi + ((size_t)(b * 512 + sK)) * 2048 + h * 128 + 64 + ch;
    const float* sQs = SinT + sQ * 32;  const float* sQc = CosT + sQ * 32;
    const float* sKs = SinT + sK * 32;  const float* sKc = CosT + sK * 32;

#pragma unroll
    for (int j = 0; j < 4; ++j) {
        int i0 = (ch >> 1) + j * 4;           // pair index base
        // Q
        bf16x8 v = *(const bf16x8*)(qsrc + j * 8);
        f32x4 sn = *(const f32x4*)(sQs + i0);
        f32x4 cs = *(const f32x4*)(sQc + i0);
        bf16x8 o;
#pragma unroll
        for (int p = 0; p < 4; ++p) {
            float f0 = b2f(v[2 * p]), f1 = b2f(v[2 * p + 1]);
            o[2 * p]     = f2b(f0 * cs[p] - f1 * sn[p]);
            o[2 * p + 1] = f2b(f1 * cs[p] + f0 * sn[p]);
        }
        *(bf16x8*)(Qs + row * 72 + ch + j * 8) = o;
        // K
        v  = *(const bf16x8*)(ksrc + j * 8);
        sn = *(const f32x4*)(sKs + i0);
        cs = *(const f32x4*)(sKc + i0);
#pragma unroll
        for (int p = 0; p < 4; ++p) {
            float f0 = b2f(v[2 * p]), f1 = b2f(v[2 * p + 1]);
            o[2 * p]     = f2b(f0 * cs[p] - f1 * sn[p]);
            o[2 * p + 1] = f2b(f1 * cs[p] + f0 * sn[p]);
        }
        *(bf16x8*)(Ks + row * 72 + ch + j * 8) = o;
    }
    if (tid < 128)        rowNeg[tid]       = (tok[b * 512 + m0 + tid] > 0) ? 0.f : NEGV;
    else if (tid < 256)   colNeg[tid - 128] = (tok[b * 512 + n0 + (tid - 128)] > 0) ? 0.f : NEGV;
    __syncthreads();

    f32x4 acc[4][4] = {};
#pragma unroll
    for (int kk = 0; kk < 64; kk += 32) {
        bf16x8 af[4], bfr[4];
#pragma unroll
        for (int mi = 0; mi < 4; ++mi)
            af[mi] = *(const bf16x8*)(Qs + (wm + mi * 16 + r16) * 72 + kk + quad * 8);
#pragma unroll
        for (int ni = 0; ni < 4; ++ni)
            bfr[ni] = *(const bf16x8*)(Ks + (wn + ni * 16 + r16) * 72 + kk + quad * 8);
#pragma unroll
        for (int mi = 0; mi < 4; ++mi)
#pragma unroll
            for (int ni = 0; ni < 4; ++ni)
                acc[mi][ni] = __builtin_amdgcn_mfma_f32_16x16x32_bf16(
                    af[mi], bfr[ni], acc[mi][ni], 0, 0, 0);
    }

    float* obase = out + (size_t)bh * 512 * 512;
#pragma unroll
    for (int mi = 0; mi < 4; ++mi)
#pragma unroll
        for (int ni = 0; ni < 4; ++ni) {
            int n = n0 + wn + ni * 16 + r16;
            float cn = colNeg[n - n0];
#pragma unroll
            for (int r = 0; r < 4; ++r) {
                int m = m0 + wm + mi * 16 + quad * 4 + r;
                float v = acc[mi][ni][r] * 0.125f - rowNeg[m - m0] - cn
                          - ((m > n) ? NEGV : 0.0f);
                obase[(size_t)m * 512 + n] = v;
            }
        }

    if (h == 0) {    // fused tri_mask (one head's worth of blocks covers it)
        float* o2 = out2 + (size_t)b * 512 * 512;
#pragma unroll
        for (int mi = 0; mi < 4; ++mi)
#pragma unroll
            for (int ni = 0; ni < 4; ++ni) {
                int n = n0 + wn + ni * 16 + r16;
                float mn = (colNeg[n - n0] == 0.f) ? 1.f : 0.f;
#pragma unroll
                for (int r = 0; r < 4; ++r) {
                    int m = m0 + wm + mi * 16 + quad * 4 + r;
                    float mm = (rowNeg[m - m0] == 0.f) ? 1.f : 0.f;
                    o2[(size_t)m * 512 + n] = (m > n) ? 0.f : (mm * mn);
                }
            }
    }
}

// ---------------------------------------------------------------------------
extern "C" void kernel_launch(void* const* d_in, const int* in_sizes, int n_in,
                              void* d_out, int out_size, void* d_ws, size_t ws_size,
                              hipStream_t stream) {
    const float* hidden = (const float*)d_in[0];   // (8,512,768) fp32
    const int*   tok    = (const int*)d_in[1];     // (8,512) int32
    const float* W      = (const float*)d_in[2];   // (768,2048) fp32
    const float* bias   = (const float*)d_in[3];   // (2048,) fp32
    float* out  = (float*)d_out;                   // logits: 33,554,432 floats
    float* out2 = out + 33554432;                  // tri_mask: 2,097,152 floats

    // workspace layout:
    //   [0, 16M)           QKi  bf16 4096x2048
    //   [16M, +6.29M)      Xb   bf16 4096x768
    //   [23.07M, +3.15M)   Wt   bf16 2048x768
    //   [26.21M, +64K)     SinT fp32 512x32
    //   [26.28M, +64K)     CosT fp32 512x32
    char* ws = (char*)d_ws;
    short* QKi  = (short*)(ws);
    short* Xb   = (short*)(ws + 16777216);
    short* Wt   = (short*)(ws + 23068672);
    float* SinT = (float*)(ws + 26214400);
    float* CosT = (float*)(ws + 26279936);

    hipLaunchKernelGGL(prep_kernel,   dim3(1600), dim3(256), 0, stream, hidden, Xb, SinT, CosT);
    hipLaunchKernelGGL(transpose_w,   dim3(384),  dim3(256), 0, stream, W, Wt);
    hipLaunchKernelGGL(gemm_qk,       dim3(512),  dim3(256), 0, stream, Xb, Wt, bias, QKi);
    hipLaunchKernelGGL(logits_kernel, dim3(2048), dim3(256), 0, stream, QKi, SinT, CosT, tok, out, out2);
}

// Round 3
// 189.062 us; speedup vs baseline: 1.1117x; 1.0515x over previous
//
#include <hip/hip_runtime.h>
#include <hip/hip_bf16.h>
#include <cstdint>
#include <cstddef>

// B=8, S=512, D=768, HEADS=16, HD=64
// Pipeline (3 kernels):
//   prep:      cast hidden->bf16, sincos table, LDS-tiled W transpose->Wt bf16
//   gemm_rope: 4096x2048x768 bf16 MFMA + bias + RoPE (shfl_xor pair) epilogue,
//              writes Q,K head-major (b,h,s,64) bf16
//   logits:    128 batched 512x512x64 MFMA, global_load_lds + XOR-swizzled LDS,
//              mask epilogue, tri_mask fused into h==0 blocks
// Tolerance ~2e10 absmax (NEG=1e12) -> bf16 numerically free (R2: 0.53).

#define NEGV 1.0e12f

typedef short bf16x8 __attribute__((ext_vector_type(8)));
typedef float f32x4  __attribute__((ext_vector_type(4)));

static __device__ __forceinline__ short f2b(float x) {
    __hip_bfloat16 h = __float2bfloat16(x);
    union { __hip_bfloat16 h; short s; } u; u.h = h; return u.s;
}
static __device__ __forceinline__ float b2f(short s) {
    union { short s; __hip_bfloat16 h; } u; u.s = s; return __bfloat162float(u.h);
}
// async global->LDS: per-lane global addr, LDS dest = wave-uniform base + lane*16
static __device__ __forceinline__ void gload16(const short* g, short* l) {
    __builtin_amdgcn_global_load_lds(
        (const __attribute__((address_space(1))) void*)g,
        (__attribute__((address_space(3))) void*)l, 16, 0, 0);
}

// ---------------------------------------------------------------------------
// 1) prep: blocks [0,1536) cast hidden; [1536,1600) sincos table;
//          [1600,1984) 64x64 LDS-tiled W transpose (fp32 KxN -> bf16 NxK)
// ---------------------------------------------------------------------------
__global__ __launch_bounds__(256) void prep_kernel(const float* __restrict__ hidden,
                                                   const float* __restrict__ W,
                                                   short* __restrict__ Xb,
                                                   short* __restrict__ Wt,
                                                   float* __restrict__ SinT,
                                                   float* __restrict__ CosT) {
    __shared__ short T[64 * 68];
    int blk = blockIdx.x, tid = threadIdx.x;
    if (blk < 1536) {                          // 393,216 threads x 8 floats
        int t = blk * 256 + tid;
        const float4* hp = (const float4*)hidden;
        float4 a = hp[t * 2], c = hp[t * 2 + 1];
        bf16x8 v;
        v[0] = f2b(a.x); v[1] = f2b(a.y); v[2] = f2b(a.z); v[3] = f2b(a.w);
        v[4] = f2b(c.x); v[5] = f2b(c.y); v[6] = f2b(c.z); v[7] = f2b(c.w);
        *(bf16x8*)(Xb + t * 8) = v;
    } else if (blk < 1600) {                   // 16,384 table entries
        int u = (blk - 1536) * 256 + tid;
        int s = u >> 5, i = u & 31;
        float ang = (float)s * exp2f(-0.4152410118609203f * (float)i); // log2(1e4)/32
        float sn, cs; __sincosf(ang, &sn, &cs);
        SinT[u] = sn; CosT[u] = cs;
    } else {                                   // 384 transpose tiles
        int tb = blk - 1600;
        int k0 = (tb % 12) * 64, n0 = (tb / 12) * 64;
        int r = tid >> 2, cb = (tid & 3) * 4;
#pragma unroll
        for (int q = 0; q < 4; ++q) {
            int c = cb + q * 16;
            float4 v = *(const float4*)(W + (size_t)(k0 + r) * 2048 + n0 + c);
            short* tp = T + r * 68 + c;
            tp[0] = f2b(v.x); tp[1] = f2b(v.y); tp[2] = f2b(v.z); tp[3] = f2b(v.w);
        }
        __syncthreads();
        int n = tid >> 2, kc = (tid & 3) * 16;
        bf16x8 o0, o1;
#pragma unroll
        for (int j = 0; j < 8; ++j) {
            o0[j] = T[(kc + j) * 68 + n];
            o1[j] = T[(kc + 8 + j) * 68 + n];
        }
        short* wp = Wt + (size_t)(n0 + n) * 768 + k0 + kc;
        *(bf16x8*)wp = o0;
        *(bf16x8*)(wp + 8) = o1;
    }
}

// ---------------------------------------------------------------------------
// 2) gemm_rope: C=A@Wt^T+bias (4096x2048x768), 128x128 tile, BK=32,
//    global_load_lds staging with XOR swizzle chunk(r,c)->r*4+(c^((r>>1)&3))
//    (frag ds_read_b128 becomes 2-way = free). Epilogue: bias + RoPE via
//    __shfl_xor(v,1), store Q/K head-major bf16.
// ---------------------------------------------------------------------------
__global__ __launch_bounds__(256) void gemm_rope(const short* __restrict__ A,
                                                 const short* __restrict__ Bt,
                                                 const float* __restrict__ bias,
                                                 const float* __restrict__ SinT,
                                                 const float* __restrict__ CosT,
                                                 short* __restrict__ Qb,
                                                 short* __restrict__ Kb) {
    __shared__ short As[128 * 32];
    __shared__ short Bs[128 * 32];
    const int m0 = (blockIdx.x >> 4) * 128;   // 32 m-tiles
    const int n0 = (blockIdx.x & 15) * 128;   // 16 n-tiles
    const int tid  = threadIdx.x;
    const int wave = tid >> 6, lane = tid & 63;
    const int quad = lane >> 4, r16 = lane & 15;
    const int wm = (wave >> 1) * 64, wn = (wave & 1) * 64;

    // staging: wave w rows [w*32,w*32+32); lane -> row w*32+(l>>2)(+16),
    // global chunk col swizzled: c = (l&3) ^ ((l>>3)&3)
    const int swc = ((lane & 3) ^ ((lane >> 3) & 3)) * 8;  // shorts
    const int r0  = wave * 32 + (lane >> 2);
    const short* gA0 = A  + (size_t)(m0 + r0) * 768 + swc;
    const short* gA1 = A  + (size_t)(m0 + r0 + 16) * 768 + swc;
    const short* gB0 = Bt + (size_t)(n0 + r0) * 768 + swc;
    const short* gB1 = Bt + (size_t)(n0 + r0 + 16) * 768 + swc;
    short* lA0 = As + wave * 1024;
    short* lA1 = As + wave * 1024 + 512;
    short* lB0 = Bs + wave * 1024;
    short* lB1 = Bs + wave * 1024 + 512;

    const int sw16 = (r16 >> 1) & 3;          // frag-read swizzle key

    f32x4 acc[4][4] = {};
    for (int k0 = 0; k0 < 768; k0 += 32) {
        __syncthreads();
        gload16(gA0 + k0, lA0);
        gload16(gA1 + k0, lA1);
        gload16(gB0 + k0, lB0);
        gload16(gB1 + k0, lB1);
        __syncthreads();

        bf16x8 af[4], bfr[4];
#pragma unroll
        for (int mi = 0; mi < 4; ++mi)
            af[mi] = *(const bf16x8*)(As + (wm + mi * 16 + r16) * 32 + (quad ^ sw16) * 8);
#pragma unroll
        for (int ni = 0; ni < 4; ++ni)
            bfr[ni] = *(const bf16x8*)(Bs + (wn + ni * 16 + r16) * 32 + (quad ^ sw16) * 8);
#pragma unroll
        for (int mi = 0; mi < 4; ++mi)
#pragma unroll
            for (int ni = 0; ni < 4; ++ni)
                acc[mi][ni] = __builtin_amdgcn_mfma_f32_16x16x32_bf16(
                    af[mi], bfr[ni], acc[mi][ni], 0, 0, 0);
    }

    // epilogue: bias + RoPE + head-major store
    const int b     = m0 >> 9;
    const int s0l   = (m0 & 511) + wm + quad * 4;
    const int h     = n0 >> 7;                 // n0 in [0,2048): h = n0/128
    const int which = wn >> 6;                 // 0 -> Q half, 1 -> K half
    short* dstT = (which ? Kb : Qb) + (size_t)(b * 16 + h) * 512 * 64;
    const float sgn = (r16 & 1) ? 1.0f : -1.0f;
#pragma unroll
    for (int ni = 0; ni < 4; ++ni) {
        int col = n0 + wn + ni * 16 + r16;
        float bv = bias[col];
        int d  = ni * 16 + r16;
        int ii = d >> 1;
#pragma unroll
        for (int mi = 0; mi < 4; ++mi)
#pragma unroll
            for (int r = 0; r < 4; ++r) {
                int s = s0l + mi * 16 + r;
                float v  = acc[mi][ni][r] + bv;
                float pv = __shfl_xor(v, 1);   // partner element of the RoPE pair
                float sn = SinT[s * 32 + ii];
                float cs = CosT[s * 32 + ii];
                dstT[(size_t)s * 64 + d] = f2b(v * cs + sgn * pv * sn);
            }
    }
}

// ---------------------------------------------------------------------------
// 3) logits: per (b,h, 128x128 tile) Q@K^T (K=64). global_load_lds staging,
//    XOR swizzle chunk(r,c)->r*8+(c^(r&7)) -> 2-way frag reads (free).
//    Epilogue: /8 - rowNeg - colNeg - causal; tri_mask fused at h==0.
// ---------------------------------------------------------------------------
__global__ __launch_bounds__(256) void logits_kernel(const short* __restrict__ Qb,
                                                     const short* __restrict__ Kb,
                                                     const int* __restrict__ tok,
                                                     float* __restrict__ out,
                                                     float* __restrict__ out2) {
    __shared__ short Qs[128 * 64];
    __shared__ short Ks[128 * 64];
    __shared__ float rowNeg[128];
    __shared__ float colNeg[128];

    int blk = blockIdx.x;                 // 2048 = 128 (b*h) * 4 * 4
    int nt = blk & 3, mt = (blk >> 2) & 3, bh = blk >> 4;
    int b = bh >> 4, h = bh & 15;
    int m0 = mt * 128, n0 = nt * 128;

    const int tid  = threadIdx.x;
    const int wave = tid >> 6, lane = tid & 63;
    const int quad = lane >> 4, r16 = lane & 15;
    const int wm = (wave >> 1) * 64, wn = (wave & 1) * 64;

    // staging: waves 0,1 -> Q; waves 2,3 -> K. 8 calls x 64 chunks each.
    const short* gsrc = (wave < 2)
        ? Qb + ((size_t)bh * 512 + m0) * 64
        : Kb + ((size_t)bh * 512 + n0) * 64;
    short* ldst = (wave < 2) ? Qs : Ks;
    const int wv = wave & 1;
    const int gc = ((lane & 7) ^ (lane >> 3)) * 8;   // swizzled chunk col, shorts
    const int rl = wv * 64 + (lane >> 3);            // + j*8 per call
#pragma unroll
    for (int j = 0; j < 8; ++j)
        gload16(gsrc + (rl + j * 8) * 64 + gc, ldst + wv * 4096 + j * 512);

    if (tid < 128)      rowNeg[tid]       = (tok[b * 512 + m0 + tid] > 0) ? 0.f : NEGV;
    else if (tid < 256) colNeg[tid - 128] = (tok[b * 512 + n0 + (tid - 128)] > 0) ? 0.f : NEGV;
    __syncthreads();

    const int sw8 = r16 & 7;              // frag swizzle key (r&7 == r16&7)
    f32x4 acc[4][4] = {};
#pragma unroll
    for (int kb = 0; kb < 2; ++kb) {      // kk = kb*32 -> chunkcol quad + kb*4
        bf16x8 af[4], bfr[4];
#pragma unroll
        for (int mi = 0; mi < 4; ++mi)
            af[mi] = *(const bf16x8*)(Qs + (wm + mi * 16 + r16) * 64
                                         + ((quad + kb * 4) ^ sw8) * 8);
#pragma unroll
        for (int ni = 0; ni < 4; ++ni)
            bfr[ni] = *(const bf16x8*)(Ks + (wn + ni * 16 + r16) * 64
                                          + ((quad + kb * 4) ^ sw8) * 8);
#pragma unroll
        for (int mi = 0; mi < 4; ++mi)
#pragma unroll
            for (int ni = 0; ni < 4; ++ni)
                acc[mi][ni] = __builtin_amdgcn_mfma_f32_16x16x32_bf16(
                    af[mi], bfr[ni], acc[mi][ni], 0, 0, 0);
    }

    float* obase = out + (size_t)bh * 512 * 512;
#pragma unroll
    for (int mi = 0; mi < 4; ++mi)
#pragma unroll
        for (int ni = 0; ni < 4; ++ni) {
            int n = n0 + wn + ni * 16 + r16;
            float cn = colNeg[n - n0];
#pragma unroll
            for (int r = 0; r < 4; ++r) {
                int m = m0 + wm + mi * 16 + quad * 4 + r;
                float v = acc[mi][ni][r] * 0.125f - rowNeg[m - m0] - cn
                          - ((m > n) ? NEGV : 0.0f);
                obase[(size_t)m * 512 + n] = v;
            }
        }

    if (h == 0) {    // fused tri_mask
        float* o2 = out2 + (size_t)b * 512 * 512;
#pragma unroll
        for (int mi = 0; mi < 4; ++mi)
#pragma unroll
            for (int ni = 0; ni < 4; ++ni) {
                int n = n0 + wn + ni * 16 + r16;
                float mn = (colNeg[n - n0] == 0.f) ? 1.f : 0.f;
#pragma unroll
                for (int r = 0; r < 4; ++r) {
                    int m = m0 + wm + mi * 16 + quad * 4 + r;
                    float mm = (rowNeg[m - m0] == 0.f) ? 1.f : 0.f;
                    o2[(size_t)m * 512 + n] = (m > n) ? 0.f : (mm * mn);
                }
            }
    }
}

// ---------------------------------------------------------------------------
extern "C" void kernel_launch(void* const* d_in, const int* in_sizes, int n_in,
                              void* d_out, int out_size, void* d_ws, size_t ws_size,
                              hipStream_t stream) {
    const float* hidden = (const float*)d_in[0];   // (8,512,768) fp32
    const int*   tok    = (const int*)d_in[1];     // (8,512) int32
    const float* W      = (const float*)d_in[2];   // (768,2048) fp32
    const float* bias   = (const float*)d_in[3];   // (2048,) fp32
    float* out  = (float*)d_out;                   // logits: 33,554,432 floats
    float* out2 = out + 33554432;                  // tri_mask: 2,097,152 floats

    // workspace layout (~26.3 MiB):
    //   [0, 6.29M)        Xb   bf16 4096x768
    //   [6.29M, +3.15M)   Wt   bf16 2048x768
    //   [9.44M, +64K)     SinT fp32 512x32
    //   [9.50M, +64K)     CosT fp32 512x32
    //   [9.57M, +8.39M)   Qb   bf16 (B,H,S,64)
    //   [17.96M, +8.39M)  Kb   bf16 (B,H,S,64)
    char* ws = (char*)d_ws;
    short* Xb   = (short*)(ws);
    short* Wt   = (short*)(ws + 6291456);
    float* SinT = (float*)(ws + 9437184);
    float* CosT = (float*)(ws + 9502720);
    short* Qb   = (short*)(ws + 9568256);
    short* Kb   = (short*)(ws + 17956864);

    hipLaunchKernelGGL(prep_kernel,   dim3(1984), dim3(256), 0, stream,
                       hidden, W, Xb, Wt, SinT, CosT);
    hipLaunchKernelGGL(gemm_rope,     dim3(512),  dim3(256), 0, stream,
                       Xb, Wt, bias, SinT, CosT, Qb, Kb);
    hipLaunchKernelGGL(logits_kernel, dim3(2048), dim3(256), 0, stream,
                       Qb, Kb, tok, out, out2);
}